// Round 10
// baseline (171.678 us; speedup 1.0000x reference)
//
#include <hip/hip_runtime.h>

#define N_NODESC 5000
#define N_EDGESC 8000
#define NCFG 32
#define HDIM 64
#define NF_DIM 140
#define OPE_DIM 8
#define XN_DIM 148
#define CF_DIM 24
#define NBLK 1250            // one wave per node: 1250 blocks x 4 waves = 5000 waves

using f32x4 = __attribute__((ext_vector_type(4))) float;
using bf16x8 = __attribute__((ext_vector_type(8))) short;

__device__ __forceinline__ ushort f2b(float f) {
    uint u = __float_as_uint(f);
    u += 0x7FFF + ((u >> 16) & 1);
    return (ushort)(u >> 16);
}
__device__ __forceinline__ float b2f(ushort u) {
    return __uint_as_float(((uint)u) << 16);
}

// ---------------- single-dispatch graph build (deg+scan+fill in LDS) ----------------
__global__ __launch_bounds__(1024) void k_graph(const int* __restrict__ ei,
                                                int* __restrict__ row_ptr,
                                                int* __restrict__ col) {
    __shared__ int sdeg[N_NODESC];   // 20 KB: degree, then reused as fill cursor
    __shared__ int ssum[1024];
    int t = threadIdx.x;
    for (int i = t; i < N_NODESC; i += 1024) sdeg[i] = 0;
    __syncthreads();
    for (int e = t; e < 2 * N_EDGESC; e += 1024) {
        int d = (e < N_EDGESC) ? ei[2 * e + 1] : ei[2 * (e - N_EDGESC)];
        atomicAdd(&sdeg[d], 1);
    }
    __syncthreads();
    const int per = (N_NODESC + 1023) / 1024;  // 5
    int vals[8];
    int loc = 0;
    for (int i = 0; i < per; ++i) {
        int idx = t * per + i;
        int v = (idx < N_NODESC) ? sdeg[idx] : 0;
        vals[i] = loc;
        loc += v;
    }
    ssum[t] = loc;
    __syncthreads();
    for (int s = 1; s < 1024; s <<= 1) {
        int v = (t >= s) ? ssum[t - s] : 0;
        __syncthreads();
        ssum[t] += v;
        __syncthreads();
    }
    int excl = ssum[t] - loc;
    for (int i = 0; i < per; ++i) {
        int idx = t * per + i;
        if (idx < N_NODESC) row_ptr[idx] = excl + vals[i];
    }
    if (t == 1023) row_ptr[N_NODESC] = ssum[1023];
    __syncthreads();
    for (int i = 0; i < per; ++i) {   // reuse sdeg as fill cursor = row start
        int idx = t * per + i;
        if (idx < N_NODESC) sdeg[idx] = excl + vals[i];
    }
    __syncthreads();
    for (int e = t; e < 2 * N_EDGESC; e += 1024) {
        int s, d;
        if (e < N_EDGESC) { s = ei[2 * e]; d = ei[2 * e + 1]; }
        else { int e2 = e - N_EDGESC; s = ei[2 * e2 + 1]; d = ei[2 * e2]; }
        int pos = atomicAdd(&sdeg[d], 1);
        col[pos] = s;
    }
}

// ---------------- weight fragment pre-pack (+ config precompute, block 7) ----------------
__global__ __launch_bounds__(512) void k_pack(const float* __restrict__ skw,
                                              const float* __restrict__ wsl,
                                              const float* __restrict__ wnl,
                                              const float* __restrict__ cf,
                                              const float* __restrict__ Ws0,
                                              const float* __restrict__ Wn0,
                                              const float* __restrict__ b0,
                                              ushort* __restrict__ frag,
                                              float* __restrict__ Fc,
                                              float* __restrict__ Gc) {
    int m = blockIdx.x;
    int t = threadIdx.x;
    if (m == 7) {
        for (int i = t; i < NCFG * HDIM; i += 512) {
            int c = i >> 6, k = i & 63;
            float f = b0[k], g = 0.f;
            for (int d = 0; d < CF_DIM; ++d) {
                float v = cf[c * CF_DIM + d];
                f += v * Ws0[(XN_DIM + d) * HDIM + k];
                g += v * Wn0[(XN_DIM + d) * HDIM + k];
            }
            Fc[i] = f;
            Gc[i] = g;
        }
        return;
    }
    const float* W;
    switch (m) {
        case 0: W = skw; break;
        case 1: W = wsl; break;
        case 2: W = wnl; break;
        case 3: W = skw + 4096; break;
        case 4: W = wsl + 4096; break;
        case 5: W = wnl + 4096; break;
        default: W = skw + 8192; break;
    }
    int ktnt = t >> 6, lane = t & 63;
    int kt = ktnt >> 2, nt = ktnt & 3;
    int g = lane >> 4, row16 = lane & 15;
    bf16x8 v;
#pragma unroll
    for (int j = 0; j < 8; ++j)
        v[j] = (short)f2b(W[(kt * 32 + g * 8 + j) * HDIM + nt * 16 + row16]);
    *reinterpret_cast<bf16x8*>(frag + (size_t)m * 4096 + (size_t)t * 8) = v;
}

// ---------------- layer-0 neighbor projection: yn = xn @ Wn0_top ----------------
__global__ void k_proj(const float* __restrict__ nf, const int* __restrict__ opcode,
                       const float* __restrict__ op_emb,
                       const float* __restrict__ Wn0, float* __restrict__ yn) {
    int t = blockIdx.x * blockDim.x + threadIdx.x;
    if (t >= N_NODESC * HDIM) return;
    int n = t >> 6, k = t & 63;
    const float* x = nf + (size_t)n * NF_DIM;
    float y = 0.f;
    for (int d = 0; d < NF_DIM; ++d) y += x[d] * Wn0[d * HDIM + k];
    const float* oe = op_emb + (size_t)opcode[n] * OPE_DIM;
#pragma unroll
    for (int d = 0; d < OPE_DIM; ++d) y += oe[d] * Wn0[(NF_DIM + d) * HDIM + k];
    yn[t] = y;
}

// ---------------- fused xs-proj + En-gather + h0 build + skip0 (one wave per node) ----------------
__global__ __launch_bounds__(256) void k_h0skip(
    const float* __restrict__ nf, const int* __restrict__ opcode,
    const float* __restrict__ op_emb, const float* __restrict__ Ws0,
    const float* __restrict__ yn,
    const float* __restrict__ Fc, const float* __restrict__ Gc,
    const int* __restrict__ row_ptr, const int* __restrict__ col,
    const ushort* __restrict__ fragSk, const float* __restrict__ skB,
    ushort* __restrict__ h0, float* __restrict__ partials) {
    __shared__ float sred[4][NCFG * HDIM];
    __shared__ float sen[4][HDIM];
    int lane = threadIdx.x & 63;
    int row16 = lane & 15, g = lane >> 4;
    int w = threadIdx.x >> 6;
    int n = (blockIdx.x * 256 + threadIdx.x) >> 6;

    // xs(n, lane): self projection inline (Ws0 rows L2-hot, 256B coalesced per d)
    const float* x = nf + (size_t)n * NF_DIM;
    float xsv = 0.f;
    for (int d = 0; d < NF_DIM; ++d) xsv += x[d] * Ws0[d * HDIM + lane];
    const float* oe = op_emb + (size_t)opcode[n] * OPE_DIM;
#pragma unroll
    for (int d = 0; d < OPE_DIM; ++d) xsv += oe[d] * Ws0[(NF_DIM + d) * HDIM + lane];

    // gather mean of neighbor yn rows (4B/lane, 256B/neighbor coalesced)
    int rs = row_ptr[n], re = row_ptr[n + 1];
    float acc = 0.f;
    for (int e = rs; e < re; ++e) acc += yn[(size_t)col[e] * HDIM + lane];
    float inv = (re > rs) ? 1.f / (float)(re - rs) : 0.f;
    float sc = (re > rs) ? 1.f : 0.f;
    sen[w][lane] = xsv + acc * inv;
    asm volatile("s_waitcnt lgkmcnt(0)" ::: "memory");

    bf16x8 bSk[2][4];
#pragma unroll
    for (int kt = 0; kt < 2; ++kt)
#pragma unroll
        for (int nt = 0; nt < 4; ++nt)
            bSk[kt][nt] = *reinterpret_cast<const bf16x8*>(
                fragSk + ((kt * 4 + nt) * 64 + lane) * 8);
    float sb[4];
#pragma unroll
    for (int nt = 0; nt < 4; ++nt) sb[nt] = skB[nt * 16 + row16];

    float en[2][8];
#pragma unroll
    for (int kt = 0; kt < 2; ++kt) {
        float4 e0 = *(const float4*)&sen[w][kt * 32 + g * 8];
        float4 e1 = *(const float4*)&sen[w][kt * 32 + g * 8 + 4];
        en[kt][0] = e0.x; en[kt][1] = e0.y; en[kt][2] = e0.z; en[kt][3] = e0.w;
        en[kt][4] = e1.x; en[kt][5] = e1.y; en[kt][6] = e1.z; en[kt][7] = e1.w;
    }

    float fcv[2][2][8], gcv[2][2][8];
#pragma unroll
    for (int mt = 0; mt < 2; ++mt)
#pragma unroll
        for (int kt = 0; kt < 2; ++kt) {
            int base = (row16 + 16 * mt) * HDIM + kt * 32 + g * 8;
            float4 f0 = *(const float4*)&Fc[base];
            float4 f1 = *(const float4*)&Fc[base + 4];
            float4 g0 = *(const float4*)&Gc[base];
            float4 g1 = *(const float4*)&Gc[base + 4];
            fcv[mt][kt][0] = f0.x; fcv[mt][kt][1] = f0.y; fcv[mt][kt][2] = f0.z; fcv[mt][kt][3] = f0.w;
            fcv[mt][kt][4] = f1.x; fcv[mt][kt][5] = f1.y; fcv[mt][kt][6] = f1.z; fcv[mt][kt][7] = f1.w;
            gcv[mt][kt][0] = g0.x; gcv[mt][kt][1] = g0.y; gcv[mt][kt][2] = g0.z; gcv[mt][kt][3] = g0.w;
            gcv[mt][kt][4] = g1.x; gcv[mt][kt][5] = g1.y; gcv[mt][kt][6] = g1.z; gcv[mt][kt][7] = g1.w;
        }

    bf16x8 aH[2][2];
#pragma unroll
    for (int mt = 0; mt < 2; ++mt)
#pragma unroll
        for (int kt = 0; kt < 2; ++kt) {
            bf16x8 a;
#pragma unroll
            for (int j = 0; j < 8; ++j) {
                float hv = fmaxf(en[kt][j] + fcv[mt][kt][j] + sc * gcv[mt][kt][j], 0.f);
                a[j] = (short)f2b(hv);
            }
            aH[mt][kt] = a;
            *reinterpret_cast<bf16x8*>(
                h0 + (size_t)n * (NCFG * HDIM) + (row16 + 16 * mt) * HDIM + kt * 32 + g * 8) = a;
        }
    f32x4 skipAcc[2][4];
#pragma unroll
    for (int mt = 0; mt < 2; ++mt)
#pragma unroll
        for (int nt = 0; nt < 4; ++nt) {
            f32x4 c2 = f32x4{0.f, 0.f, 0.f, 0.f};
#pragma unroll
            for (int kt = 0; kt < 2; ++kt)
                c2 = __builtin_amdgcn_mfma_f32_16x16x32_bf16(aH[mt][kt], bSk[kt][nt], c2, 0, 0, 0);
#pragma unroll
            for (int r = 0; r < 4; ++r)
                skipAcc[mt][nt][r] = fmaxf(c2[r] + sb[nt], 0.f);
        }

#pragma unroll
    for (int mt = 0; mt < 2; ++mt)
#pragma unroll
        for (int nt = 0; nt < 4; ++nt)
#pragma unroll
            for (int r = 0; r < 4; ++r)
                sred[w][(16 * mt + 4 * g + r) * HDIM + 16 * nt + row16] = skipAcc[mt][nt][r];
    __syncthreads();
    float* pb = partials + (size_t)blockIdx.x * (NCFG * HDIM);
#pragma unroll
    for (int q = 0; q < 2; ++q) {
        int p = threadIdx.x * 8 + q * 4;
        f32x4 s = *(const f32x4*)&sred[0][p];
        s += *(const f32x4*)&sred[1][p];
        s += *(const f32x4*)&sred[2][p];
        s += *(const f32x4*)&sred[3][p];
        *(f32x4*)&pb[p] = s;
    }
}

// ---------------- fused SAGE layer + out-skip (one wave per node, union LDS) ----------------
template <int STORE_H>
__global__ __launch_bounds__(256) void k_sage_mfma(
    const ushort* __restrict__ h_in, ushort* __restrict__ h_out,
    const ushort* __restrict__ fragWs, const ushort* __restrict__ fragWn,
    const ushort* __restrict__ fragSk,
    const float* __restrict__ bias, const float* __restrict__ skB,
    const int* __restrict__ row_ptr, const int* __restrict__ col,
    float* __restrict__ partials) {
    __shared__ __align__(16) char smem_raw[NCFG * HDIM * 4 * 4];
    int lane = threadIdx.x & 63;
    int row16 = lane & 15, g = lane >> 4;
    int w = threadIdx.x >> 6;
    int n = (blockIdx.x * 256 + threadIdx.x) >> 6;
    ushort* st = (ushort*)smem_raw + (size_t)w * (32 * 72);
    float* sredw = (float*)smem_raw;

    bf16x8 bWs[2][4], bWn[2][4];
#pragma unroll
    for (int kt = 0; kt < 2; ++kt)
#pragma unroll
        for (int nt = 0; nt < 4; ++nt) {
            int fo = ((kt * 4 + nt) * 64 + lane) * 8;
            bWs[kt][nt] = *reinterpret_cast<const bf16x8*>(fragWs + fo);
            bWn[kt][nt] = *reinterpret_cast<const bf16x8*>(fragWn + fo);
        }
    float bb[4], sb[4];
#pragma unroll
    for (int nt = 0; nt < 4; ++nt) {
        bb[nt] = bias[nt * 16 + row16];
        sb[nt] = skB[nt * 16 + row16];
    }

    int loff[2][2];
#pragma unroll
    for (int mt = 0; mt < 2; ++mt)
#pragma unroll
        for (int kt = 0; kt < 2; ++kt)
            loff[mt][kt] = (row16 + 16 * mt) * HDIM + kt * 32 + g * 8;

    const ushort* hb = h_in + (size_t)n * (NCFG * HDIM);
    bf16x8 aS[2][2];
#pragma unroll
    for (int mt = 0; mt < 2; ++mt)
#pragma unroll
        for (int kt = 0; kt < 2; ++kt)
            aS[mt][kt] = *reinterpret_cast<const bf16x8*>(hb + loff[mt][kt]);

    float agg[2][2][8];
#pragma unroll
    for (int mt = 0; mt < 2; ++mt)
#pragma unroll
        for (int kt = 0; kt < 2; ++kt)
#pragma unroll
            for (int j = 0; j < 8; ++j) agg[mt][kt][j] = 0.f;
    int rs = row_ptr[n], re = row_ptr[n + 1];
    for (int e = rs; e < re; ++e) {
        const ushort* nb = h_in + (size_t)col[e] * (NCFG * HDIM);
#pragma unroll
        for (int mt = 0; mt < 2; ++mt)
#pragma unroll
            for (int kt = 0; kt < 2; ++kt) {
                bf16x8 u = *reinterpret_cast<const bf16x8*>(nb + loff[mt][kt]);
#pragma unroll
                for (int j = 0; j < 8; ++j) agg[mt][kt][j] += b2f((ushort)u[j]);
            }
    }
    float inv = (re > rs) ? 1.f / (float)(re - rs) : 0.f;
    bf16x8 aA[2][2];
#pragma unroll
    for (int mt = 0; mt < 2; ++mt)
#pragma unroll
        for (int kt = 0; kt < 2; ++kt)
#pragma unroll
            for (int j = 0; j < 8; ++j)
                aA[mt][kt][j] = (short)f2b(agg[mt][kt][j] * inv);

    f32x4 C[2][4];
#pragma unroll
    for (int mt = 0; mt < 2; ++mt)
#pragma unroll
        for (int nt = 0; nt < 4; ++nt) {
            f32x4 c = f32x4{0.f, 0.f, 0.f, 0.f};
#pragma unroll
            for (int kt = 0; kt < 2; ++kt) {
                c = __builtin_amdgcn_mfma_f32_16x16x32_bf16(aS[mt][kt], bWs[kt][nt], c, 0, 0, 0);
                c = __builtin_amdgcn_mfma_f32_16x16x32_bf16(aA[mt][kt], bWn[kt][nt], c, 0, 0, 0);
            }
            C[mt][nt] = c;
        }

#pragma unroll
    for (int mt = 0; mt < 2; ++mt)
#pragma unroll
        for (int nt = 0; nt < 4; ++nt)
#pragma unroll
            for (int r = 0; r < 4; ++r) {
                float hv = fmaxf(C[mt][nt][r] + bb[nt], 0.f);
                st[(16 * mt + 4 * g + r) * 72 + 16 * nt + row16] = f2b(hv);
            }
    asm volatile("s_waitcnt lgkmcnt(0)" ::: "memory");

    if (STORE_H) {
#pragma unroll
        for (int i = 0; i < 4; ++i) {
            int e2 = i * 512 + lane * 8;
            int cc = e2 >> 6, dd = e2 & 63;
            bf16x8 v = *reinterpret_cast<const bf16x8*>(st + cc * 72 + dd);
            *reinterpret_cast<bf16x8*>(h_out + (size_t)n * (NCFG * HDIM) + e2) = v;
        }
    }

    bf16x8 aH[2][2];
#pragma unroll
    for (int mt = 0; mt < 2; ++mt)
#pragma unroll
        for (int kt = 0; kt < 2; ++kt)
            aH[mt][kt] = *reinterpret_cast<const bf16x8*>(
                st + (row16 + 16 * mt) * 72 + kt * 32 + g * 8);
    asm volatile("s_waitcnt lgkmcnt(0)" ::: "memory");

    bf16x8 bSk[2][4];
#pragma unroll
    for (int kt = 0; kt < 2; ++kt)
#pragma unroll
        for (int nt = 0; nt < 4; ++nt)
            bSk[kt][nt] = *reinterpret_cast<const bf16x8*>(
                fragSk + ((kt * 4 + nt) * 64 + lane) * 8);
    f32x4 skipAcc[2][4];
#pragma unroll
    for (int mt = 0; mt < 2; ++mt)
#pragma unroll
        for (int nt = 0; nt < 4; ++nt) {
            f32x4 c2 = f32x4{0.f, 0.f, 0.f, 0.f};
#pragma unroll
            for (int kt = 0; kt < 2; ++kt)
                c2 = __builtin_amdgcn_mfma_f32_16x16x32_bf16(aH[mt][kt], bSk[kt][nt], c2, 0, 0, 0);
#pragma unroll
            for (int r = 0; r < 4; ++r)
                skipAcc[mt][nt][r] = fmaxf(c2[r] + sb[nt], 0.f);
        }

    __syncthreads();   // all waves done with stage region before sred overlay
#pragma unroll
    for (int mt = 0; mt < 2; ++mt)
#pragma unroll
        for (int nt = 0; nt < 4; ++nt)
#pragma unroll
            for (int r = 0; r < 4; ++r)
                sredw[(size_t)w * (NCFG * HDIM) +
                      (16 * mt + 4 * g + r) * HDIM + 16 * nt + row16] = skipAcc[mt][nt][r];
    __syncthreads();
    float* pb = partials + (size_t)blockIdx.x * (NCFG * HDIM);
#pragma unroll
    for (int q = 0; q < 2; ++q) {
        int p = threadIdx.x * 8 + q * 4;
        f32x4 s = *(const f32x4*)&sredw[0 * NCFG * HDIM + p];
        s += *(const f32x4*)&sredw[1 * NCFG * HDIM + p];
        s += *(const f32x4*)&sredw[2 * NCFG * HDIM + p];
        s += *(const f32x4*)&sredw[3 * NCFG * HDIM + p];
        *(f32x4*)&pb[p] = s;
    }
}

// ---------------- reduce stage A over all 3 layers ----------------
__global__ __launch_bounds__(256) void k_redA(const float* __restrict__ pAll,
                                              float* __restrict__ part2) {
    int i = blockIdx.x * 256 + threadIdx.x;   // 0..2047
    int jb = blockIdx.y;                      // 0..31
    int l = blockIdx.z;                       // 0..2
    const int seg = (NBLK + 31) / 32;         // 40
    const float* base = pAll + (size_t)l * NBLK * (NCFG * HDIM);
    float s = 0.f;
    for (int q = 0; q < seg; ++q) {
        int b = jb * seg + q;
        if (b < NBLK) s += base[(size_t)b * (NCFG * HDIM) + i];
    }
    part2[((size_t)l * 32 + jb) * (NCFG * HDIM) + i] = s;
}

// ---------------- final MLP (stage-B reduce folded in) ----------------
__global__ void k_mlp(const float* __restrict__ part2,
                      const float* __restrict__ p1w, const float* __restrict__ p1b,
                      const float* __restrict__ p2w, const float* __restrict__ p2b,
                      const float* __restrict__ p3w, const float* __restrict__ p3b,
                      float* __restrict__ out) {
    int c = blockIdx.x;
    int t = threadIdx.x;
    __shared__ float sx[192];
    __shared__ float h1s[128];
    __shared__ float h2s[64];
    if (t < 192) {
        int l = t >> 6, k = t & 63;
        float s = 0.f;
#pragma unroll
        for (int b = 0; b < 32; ++b)
            s += part2[((size_t)l * 32 + b) * (NCFG * HDIM) + c * HDIM + k];
        sx[t] = s;
    }
    __syncthreads();
    if (t < 128) {
        float s = p1b[t];
        for (int d = 0; d < 192; ++d) s += sx[d] * p1w[d * 128 + t];
        h1s[t] = fmaxf(s, 0.f);
    }
    __syncthreads();
    if (t < 64) {
        float s = p2b[t];
        for (int d = 0; d < 128; ++d) s += h1s[d] * p2w[d * 64 + t];
        h2s[t] = fmaxf(s, 0.f);
    }
    __syncthreads();
    if (t == 0) {
        float s = p3b[0];
        for (int d = 0; d < 64; ++d) s += h2s[d] * p3w[d];
        out[c] = s;
    }
}

extern "C" void kernel_launch(void* const* d_in, const int* in_sizes, int n_in,
                              void* d_out, int out_size, void* d_ws, size_t ws_size,
                              hipStream_t stream) {
    const float* nf  = (const float*)d_in[0];
    const int*   opc = (const int*)d_in[1];
    const int*   ei  = (const int*)d_in[2];
    const float* cf  = (const float*)d_in[3];
    const float* ope = (const float*)d_in[4];
    const float* ws0 = (const float*)d_in[5];
    const float* wn0 = (const float*)d_in[6];
    const float* b0  = (const float*)d_in[7];
    const float* wsl = (const float*)d_in[8];
    const float* wnl = (const float*)d_in[9];
    const float* bl  = (const float*)d_in[10];
    const float* skw = (const float*)d_in[11];
    const float* skb = (const float*)d_in[12];
    const float* p1w = (const float*)d_in[13];
    const float* p1b = (const float*)d_in[14];
    const float* p2w = (const float*)d_in[15];
    const float* p2b = (const float*)d_in[16];
    const float* p3w = (const float*)d_in[17];
    const float* p3b = (const float*)d_in[18];
    float* out = (float*)d_out;

    char* w = (char*)d_ws;
    auto alloc = [&](size_t bytes) {
        char* p = w;
        w += (bytes + 255) & ~(size_t)255;
        return p;
    };
    int* row_ptr  = (int*)alloc((N_NODESC + 1) * 4);
    int* col      = (int*)alloc(2 * N_EDGESC * 4);
    float* yn     = (float*)alloc((size_t)N_NODESC * HDIM * 4);
    float* Fc     = (float*)alloc(NCFG * HDIM * 4);
    float* Gc     = (float*)alloc(NCFG * HDIM * 4);
    float* part2  = (float*)alloc(3 * 32 * NCFG * HDIM * 4);
    ushort* frag  = (ushort*)alloc(7 * 4096 * 2);
    float* pAll   = (float*)alloc((size_t)3 * NBLK * NCFG * HDIM * 4);
    ushort* h0    = (ushort*)alloc((size_t)N_NODESC * NCFG * HDIM * 2);
    ushort* h1    = (ushort*)alloc((size_t)N_NODESC * NCFG * HDIM * 2);

    float* p0 = pAll;
    float* p1 = pAll + (size_t)NBLK * (NCFG * HDIM);
    float* p2 = pAll + (size_t)2 * NBLK * (NCFG * HDIM);

    k_graph<<<1, 1024, 0, stream>>>(ei, row_ptr, col);
    k_pack<<<8, 512, 0, stream>>>(skw, wsl, wnl, cf, ws0, wn0, b0, frag, Fc, Gc);
    k_proj<<<(N_NODESC * HDIM + 255) / 256, 256, 0, stream>>>(nf, opc, ope, wn0, yn);

    k_h0skip<<<NBLK, 256, 0, stream>>>(nf, opc, ope, ws0, yn, Fc, Gc,
                                       row_ptr, col, frag, skb, h0, p0);
    k_sage_mfma<1><<<NBLK, 256, 0, stream>>>(
        h0, h1, frag + 1 * 4096, frag + 2 * 4096, frag + 3 * 4096,
        bl, skb + 64, row_ptr, col, p1);
    k_sage_mfma<0><<<NBLK, 256, 0, stream>>>(
        h1, (ushort*)nullptr, frag + 4 * 4096, frag + 5 * 4096, frag + 6 * 4096,
        bl + 64, skb + 2 * 64, row_ptr, col, p2);

    dim3 gA(8, 32, 3);
    k_redA<<<gA, 256, 0, stream>>>(pAll, part2);
    k_mlp<<<NCFG, 256, 0, stream>>>(part2, p1w, p1b, p2w, p2b, p3w, p3b, out);
}

// Round 11
// 160.712 us; speedup vs baseline: 1.0682x; 1.0682x over previous
//
#include <hip/hip_runtime.h>

#define N_NODESC 5000
#define N_EDGESC 8000
#define NCFG 32
#define HDIM 64
#define NF_DIM 140
#define OPE_DIM 8
#define XN_DIM 148
#define CF_DIM 24
#define NBLK 1250            // one wave per node: 1250 blocks x 4 waves = 5000 waves

using f32x4 = __attribute__((ext_vector_type(4))) float;
using bf16x8 = __attribute__((ext_vector_type(8))) short;

__device__ __forceinline__ ushort f2b(float f) {
    uint u = __float_as_uint(f);
    u += 0x7FFF + ((u >> 16) & 1);
    return (ushort)(u >> 16);
}
__device__ __forceinline__ float b2f(ushort u) {
    return __uint_as_float(((uint)u) << 16);
}

// ---------------- graph build ----------------
__global__ void k_deg(const int* __restrict__ ei, int* __restrict__ deg) {
    int t = blockIdx.x * blockDim.x + threadIdx.x;
    if (t >= 2 * N_EDGESC) return;
    int d;
    if (t < N_EDGESC) d = ei[2 * t + 1];
    else d = ei[2 * (t - N_EDGESC)];
    atomicAdd(&deg[d], 1);
}

__global__ void k_scan(const int* __restrict__ deg, int* __restrict__ row_ptr) {
    __shared__ int ssum[1024];
    int t = threadIdx.x;
    const int per = (N_NODESC + 1023) / 1024;
    int vals[8];
    int loc = 0;
    for (int i = 0; i < per; ++i) {
        int idx = t * per + i;
        int v = (idx < N_NODESC) ? deg[idx] : 0;
        vals[i] = loc;
        loc += v;
    }
    ssum[t] = loc;
    __syncthreads();
    for (int s = 1; s < 1024; s <<= 1) {
        int v = (t >= s) ? ssum[t - s] : 0;
        __syncthreads();
        ssum[t] += v;
        __syncthreads();
    }
    int excl = ssum[t] - loc;
    for (int i = 0; i < per; ++i) {
        int idx = t * per + i;
        if (idx < N_NODESC) row_ptr[idx] = excl + vals[i];
    }
    if (t == 1023) row_ptr[N_NODESC] = ssum[1023];
}

__global__ void k_fill(const int* __restrict__ ei, const int* __restrict__ row_ptr,
                       int* __restrict__ fill, int* __restrict__ col) {
    int t = blockIdx.x * blockDim.x + threadIdx.x;
    if (t >= 2 * N_EDGESC) return;
    int s, d;
    if (t < N_EDGESC) { s = ei[2 * t]; d = ei[2 * t + 1]; }
    else { int e = t - N_EDGESC; s = ei[2 * e + 1]; d = ei[2 * e]; }
    int pos = atomicAdd(&fill[d], 1);
    col[row_ptr[d] + pos] = s;
}

// ---------------- weight fragment pre-pack (+ config precompute, block 7) ----------------
__global__ __launch_bounds__(512) void k_pack(const float* __restrict__ skw,
                                              const float* __restrict__ wsl,
                                              const float* __restrict__ wnl,
                                              const float* __restrict__ cf,
                                              const float* __restrict__ Ws0,
                                              const float* __restrict__ Wn0,
                                              const float* __restrict__ b0,
                                              ushort* __restrict__ frag,
                                              float* __restrict__ Fc,
                                              float* __restrict__ Gc) {
    int m = blockIdx.x;
    int t = threadIdx.x;
    if (m == 7) {
        for (int i = t; i < NCFG * HDIM; i += 512) {
            int c = i >> 6, k = i & 63;
            float f = b0[k], g = 0.f;
            for (int d = 0; d < CF_DIM; ++d) {
                float v = cf[c * CF_DIM + d];
                f += v * Ws0[(XN_DIM + d) * HDIM + k];
                g += v * Wn0[(XN_DIM + d) * HDIM + k];
            }
            Fc[i] = f;
            Gc[i] = g;
        }
        return;
    }
    const float* W;
    switch (m) {
        case 0: W = skw; break;
        case 1: W = wsl; break;
        case 2: W = wnl; break;
        case 3: W = skw + 4096; break;
        case 4: W = wsl + 4096; break;
        case 5: W = wnl + 4096; break;
        default: W = skw + 8192; break;
    }
    int ktnt = t >> 6, lane = t & 63;
    int kt = ktnt >> 2, nt = ktnt & 3;
    int g = lane >> 4, row16 = lane & 15;
    bf16x8 v;
#pragma unroll
    for (int j = 0; j < 8; ++j)
        v[j] = (short)f2b(W[(kt * 32 + g * 8 + j) * HDIM + nt * 16 + row16]);
    *reinterpret_cast<bf16x8*>(frag + (size_t)m * 4096 + (size_t)t * 8) = v;
}

// ---------------- layer-0: project THEN aggregate (mean is linear) ----------------
__global__ void k_proj(const float* __restrict__ nf, const int* __restrict__ opcode,
                       const float* __restrict__ op_emb,
                       const float* __restrict__ Ws0, const float* __restrict__ Wn0,
                       float* __restrict__ xs, float* __restrict__ yn) {
    int t = blockIdx.x * blockDim.x + threadIdx.x;
    if (t >= N_NODESC * HDIM) return;
    int n = t >> 6, k = t & 63;
    const float* x = nf + (size_t)n * NF_DIM;
    float s = 0.f, y = 0.f;
    for (int d = 0; d < NF_DIM; ++d) {
        float v = x[d];
        s += v * Ws0[d * HDIM + k];
        y += v * Wn0[d * HDIM + k];
    }
    const float* oe = op_emb + (size_t)opcode[n] * OPE_DIM;
#pragma unroll
    for (int d = 0; d < OPE_DIM; ++d) {
        float v = oe[d];
        s += v * Ws0[(NF_DIM + d) * HDIM + k];
        y += v * Wn0[(NF_DIM + d) * HDIM + k];
    }
    xs[t] = s;
    yn[t] = y;
}

// ---------------- fused En-gather + h0 build + skip0 (one wave per node) ----------------
__global__ __launch_bounds__(256) void k_h0skip(
    const float* __restrict__ xs, const float* __restrict__ yn,
    const float* __restrict__ Fc, const float* __restrict__ Gc,
    const int* __restrict__ row_ptr, const int* __restrict__ col,
    const ushort* __restrict__ fragSk, const float* __restrict__ skB,
    ushort* __restrict__ h0, float* __restrict__ partials) {
    __shared__ float sred[4][NCFG * HDIM];
    __shared__ float sen[4][HDIM];
    int lane = threadIdx.x & 63;
    int row16 = lane & 15, g = lane >> 4;
    int w = threadIdx.x >> 6;
    int n = (blockIdx.x * 256 + threadIdx.x) >> 6;

    // En[lane] = xs[n][lane] + mean-gather of yn rows (256B/neighbor coalesced)
    int rs = row_ptr[n], re = row_ptr[n + 1];
    float acc = 0.f;
    for (int e = rs; e < re; ++e) acc += yn[(size_t)col[e] * HDIM + lane];
    float inv = (re > rs) ? 1.f / (float)(re - rs) : 0.f;
    float sc = (re > rs) ? 1.f : 0.f;
    sen[w][lane] = xs[(size_t)n * HDIM + lane] + acc * inv;
    asm volatile("s_waitcnt lgkmcnt(0)" ::: "memory");

    bf16x8 bSk[2][4];
#pragma unroll
    for (int kt = 0; kt < 2; ++kt)
#pragma unroll
        for (int nt = 0; nt < 4; ++nt)
            bSk[kt][nt] = *reinterpret_cast<const bf16x8*>(
                fragSk + ((kt * 4 + nt) * 64 + lane) * 8);
    float sb[4];
#pragma unroll
    for (int nt = 0; nt < 4; ++nt) sb[nt] = skB[nt * 16 + row16];

    float fcv[2][2][8], gcv[2][2][8];
#pragma unroll
    for (int mt = 0; mt < 2; ++mt)
#pragma unroll
        for (int kt = 0; kt < 2; ++kt) {
            int base = (row16 + 16 * mt) * HDIM + kt * 32 + g * 8;
            float4 f0 = *(const float4*)&Fc[base];
            float4 f1 = *(const float4*)&Fc[base + 4];
            float4 g0 = *(const float4*)&Gc[base];
            float4 g1 = *(const float4*)&Gc[base + 4];
            fcv[mt][kt][0] = f0.x; fcv[mt][kt][1] = f0.y; fcv[mt][kt][2] = f0.z; fcv[mt][kt][3] = f0.w;
            fcv[mt][kt][4] = f1.x; fcv[mt][kt][5] = f1.y; fcv[mt][kt][6] = f1.z; fcv[mt][kt][7] = f1.w;
            gcv[mt][kt][0] = g0.x; gcv[mt][kt][1] = g0.y; gcv[mt][kt][2] = g0.z; gcv[mt][kt][3] = g0.w;
            gcv[mt][kt][4] = g1.x; gcv[mt][kt][5] = g1.y; gcv[mt][kt][6] = g1.z; gcv[mt][kt][7] = g1.w;
        }

    float en[2][8];
#pragma unroll
    for (int kt = 0; kt < 2; ++kt) {
        float4 e0 = *(const float4*)&sen[w][kt * 32 + g * 8];
        float4 e1 = *(const float4*)&sen[w][kt * 32 + g * 8 + 4];
        en[kt][0] = e0.x; en[kt][1] = e0.y; en[kt][2] = e0.z; en[kt][3] = e0.w;
        en[kt][4] = e1.x; en[kt][5] = e1.y; en[kt][6] = e1.z; en[kt][7] = e1.w;
    }

    bf16x8 aH[2][2];
#pragma unroll
    for (int mt = 0; mt < 2; ++mt)
#pragma unroll
        for (int kt = 0; kt < 2; ++kt) {
            bf16x8 a;
#pragma unroll
            for (int j = 0; j < 8; ++j) {
                float hv = fmaxf(en[kt][j] + fcv[mt][kt][j] + sc * gcv[mt][kt][j], 0.f);
                a[j] = (short)f2b(hv);
            }
            aH[mt][kt] = a;
            *reinterpret_cast<bf16x8*>(
                h0 + (size_t)n * (NCFG * HDIM) + (row16 + 16 * mt) * HDIM + kt * 32 + g * 8) = a;
        }
    f32x4 skipAcc[2][4];
#pragma unroll
    for (int mt = 0; mt < 2; ++mt)
#pragma unroll
        for (int nt = 0; nt < 4; ++nt) {
            f32x4 c2 = f32x4{0.f, 0.f, 0.f, 0.f};
#pragma unroll
            for (int kt = 0; kt < 2; ++kt)
                c2 = __builtin_amdgcn_mfma_f32_16x16x32_bf16(aH[mt][kt], bSk[kt][nt], c2, 0, 0, 0);
#pragma unroll
            for (int r = 0; r < 4; ++r)
                skipAcc[mt][nt][r] = fmaxf(c2[r] + sb[nt], 0.f);
        }

#pragma unroll
    for (int mt = 0; mt < 2; ++mt)
#pragma unroll
        for (int nt = 0; nt < 4; ++nt)
#pragma unroll
            for (int r = 0; r < 4; ++r)
                sred[w][(16 * mt + 4 * g + r) * HDIM + 16 * nt + row16] = skipAcc[mt][nt][r];
    __syncthreads();
    float* pb = partials + (size_t)blockIdx.x * (NCFG * HDIM);
#pragma unroll
    for (int q = 0; q < 2; ++q) {
        int p = threadIdx.x * 8 + q * 4;
        f32x4 s = *(const f32x4*)&sred[0][p];
        s += *(const f32x4*)&sred[1][p];
        s += *(const f32x4*)&sred[2][p];
        s += *(const f32x4*)&sred[3][p];
        *(f32x4*)&pb[p] = s;
    }
}

// ---------------- fused SAGE layer + out-skip (one wave per node, union LDS) ----------------
template <int STORE_H>
__global__ __launch_bounds__(256) void k_sage_mfma(
    const ushort* __restrict__ h_in, ushort* __restrict__ h_out,
    const ushort* __restrict__ fragWs, const ushort* __restrict__ fragWn,
    const ushort* __restrict__ fragSk,
    const float* __restrict__ bias, const float* __restrict__ skB,
    const int* __restrict__ row_ptr, const int* __restrict__ col,
    float* __restrict__ partials) {
    __shared__ __align__(16) char smem_raw[NCFG * HDIM * 4 * 4];
    int lane = threadIdx.x & 63;
    int row16 = lane & 15, g = lane >> 4;
    int w = threadIdx.x >> 6;
    int n = (blockIdx.x * 256 + threadIdx.x) >> 6;
    ushort* st = (ushort*)smem_raw + (size_t)w * (32 * 72);
    float* sredw = (float*)smem_raw;

    bf16x8 bWs[2][4], bWn[2][4];
#pragma unroll
    for (int kt = 0; kt < 2; ++kt)
#pragma unroll
        for (int nt = 0; nt < 4; ++nt) {
            int fo = ((kt * 4 + nt) * 64 + lane) * 8;
            bWs[kt][nt] = *reinterpret_cast<const bf16x8*>(fragWs + fo);
            bWn[kt][nt] = *reinterpret_cast<const bf16x8*>(fragWn + fo);
        }
    float bb[4], sb[4];
#pragma unroll
    for (int nt = 0; nt < 4; ++nt) {
        bb[nt] = bias[nt * 16 + row16];
        sb[nt] = skB[nt * 16 + row16];
    }

    int loff[2][2];
#pragma unroll
    for (int mt = 0; mt < 2; ++mt)
#pragma unroll
        for (int kt = 0; kt < 2; ++kt)
            loff[mt][kt] = (row16 + 16 * mt) * HDIM + kt * 32 + g * 8;

    const ushort* hb = h_in + (size_t)n * (NCFG * HDIM);
    bf16x8 aS[2][2];
#pragma unroll
    for (int mt = 0; mt < 2; ++mt)
#pragma unroll
        for (int kt = 0; kt < 2; ++kt)
            aS[mt][kt] = *reinterpret_cast<const bf16x8*>(hb + loff[mt][kt]);

    float agg[2][2][8];
#pragma unroll
    for (int mt = 0; mt < 2; ++mt)
#pragma unroll
        for (int kt = 0; kt < 2; ++kt)
#pragma unroll
            for (int j = 0; j < 8; ++j) agg[mt][kt][j] = 0.f;
    int rs = row_ptr[n], re = row_ptr[n + 1];
    for (int e = rs; e < re; ++e) {
        const ushort* nb = h_in + (size_t)col[e] * (NCFG * HDIM);
#pragma unroll
        for (int mt = 0; mt < 2; ++mt)
#pragma unroll
            for (int kt = 0; kt < 2; ++kt) {
                bf16x8 u = *reinterpret_cast<const bf16x8*>(nb + loff[mt][kt]);
#pragma unroll
                for (int j = 0; j < 8; ++j) agg[mt][kt][j] += b2f((ushort)u[j]);
            }
    }
    float inv = (re > rs) ? 1.f / (float)(re - rs) : 0.f;
    bf16x8 aA[2][2];
#pragma unroll
    for (int mt = 0; mt < 2; ++mt)
#pragma unroll
        for (int kt = 0; kt < 2; ++kt)
#pragma unroll
            for (int j = 0; j < 8; ++j)
                aA[mt][kt][j] = (short)f2b(agg[mt][kt][j] * inv);

    f32x4 C[2][4];
#pragma unroll
    for (int mt = 0; mt < 2; ++mt)
#pragma unroll
        for (int nt = 0; nt < 4; ++nt) {
            f32x4 c = f32x4{0.f, 0.f, 0.f, 0.f};
#pragma unroll
            for (int kt = 0; kt < 2; ++kt) {
                c = __builtin_amdgcn_mfma_f32_16x16x32_bf16(aS[mt][kt], bWs[kt][nt], c, 0, 0, 0);
                c = __builtin_amdgcn_mfma_f32_16x16x32_bf16(aA[mt][kt], bWn[kt][nt], c, 0, 0, 0);
            }
            C[mt][nt] = c;
        }

#pragma unroll
    for (int mt = 0; mt < 2; ++mt)
#pragma unroll
        for (int nt = 0; nt < 4; ++nt)
#pragma unroll
            for (int r = 0; r < 4; ++r) {
                float hv = fmaxf(C[mt][nt][r] + bb[nt], 0.f);
                st[(16 * mt + 4 * g + r) * 72 + 16 * nt + row16] = f2b(hv);
            }
    asm volatile("s_waitcnt lgkmcnt(0)" ::: "memory");

    if (STORE_H) {
#pragma unroll
        for (int i = 0; i < 4; ++i) {
            int e2 = i * 512 + lane * 8;
            int cc = e2 >> 6, dd = e2 & 63;
            bf16x8 v = *reinterpret_cast<const bf16x8*>(st + cc * 72 + dd);
            *reinterpret_cast<bf16x8*>(h_out + (size_t)n * (NCFG * HDIM) + e2) = v;
        }
    }

    bf16x8 aH[2][2];
#pragma unroll
    for (int mt = 0; mt < 2; ++mt)
#pragma unroll
        for (int kt = 0; kt < 2; ++kt)
            aH[mt][kt] = *reinterpret_cast<const bf16x8*>(
                st + (row16 + 16 * mt) * 72 + kt * 32 + g * 8);
    asm volatile("s_waitcnt lgkmcnt(0)" ::: "memory");

    bf16x8 bSk[2][4];
#pragma unroll
    for (int kt = 0; kt < 2; ++kt)
#pragma unroll
        for (int nt = 0; nt < 4; ++nt)
            bSk[kt][nt] = *reinterpret_cast<const bf16x8*>(
                fragSk + ((kt * 4 + nt) * 64 + lane) * 8);
    f32x4 skipAcc[2][4];
#pragma unroll
    for (int mt = 0; mt < 2; ++mt)
#pragma unroll
        for (int nt = 0; nt < 4; ++nt) {
            f32x4 c2 = f32x4{0.f, 0.f, 0.f, 0.f};
#pragma unroll
            for (int kt = 0; kt < 2; ++kt)
                c2 = __builtin_amdgcn_mfma_f32_16x16x32_bf16(aH[mt][kt], bSk[kt][nt], c2, 0, 0, 0);
#pragma unroll
            for (int r = 0; r < 4; ++r)
                skipAcc[mt][nt][r] = fmaxf(c2[r] + sb[nt], 0.f);
        }

    __syncthreads();   // all waves done with stage region before sred overlay
#pragma unroll
    for (int mt = 0; mt < 2; ++mt)
#pragma unroll
        for (int nt = 0; nt < 4; ++nt)
#pragma unroll
            for (int r = 0; r < 4; ++r)
                sredw[(size_t)w * (NCFG * HDIM) +
                      (16 * mt + 4 * g + r) * HDIM + 16 * nt + row16] = skipAcc[mt][nt][r];
    __syncthreads();
    float* pb = partials + (size_t)blockIdx.x * (NCFG * HDIM);
#pragma unroll
    for (int q = 0; q < 2; ++q) {
        int p = threadIdx.x * 8 + q * 4;
        f32x4 s = *(const f32x4*)&sredw[0 * NCFG * HDIM + p];
        s += *(const f32x4*)&sredw[1 * NCFG * HDIM + p];
        s += *(const f32x4*)&sredw[2 * NCFG * HDIM + p];
        s += *(const f32x4*)&sredw[3 * NCFG * HDIM + p];
        *(f32x4*)&pb[p] = s;
    }
}

// ---------------- reduce stage A over all 3 layers ----------------
__global__ __launch_bounds__(256) void k_redA(const float* __restrict__ pAll,
                                              float* __restrict__ part2) {
    int i = blockIdx.x * 256 + threadIdx.x;   // 0..2047
    int jb = blockIdx.y;                      // 0..31
    int l = blockIdx.z;                       // 0..2
    const int seg = (NBLK + 31) / 32;         // 40
    const float* base = pAll + (size_t)l * NBLK * (NCFG * HDIM);
    float s = 0.f;
    for (int q = 0; q < seg; ++q) {
        int b = jb * seg + q;
        if (b < NBLK) s += base[(size_t)b * (NCFG * HDIM) + i];
    }
    part2[((size_t)l * 32 + jb) * (NCFG * HDIM) + i] = s;
}

// ---------------- final MLP (stage-B reduce folded in) ----------------
__global__ void k_mlp(const float* __restrict__ part2,
                      const float* __restrict__ p1w, const float* __restrict__ p1b,
                      const float* __restrict__ p2w, const float* __restrict__ p2b,
                      const float* __restrict__ p3w, const float* __restrict__ p3b,
                      float* __restrict__ out) {
    int c = blockIdx.x;
    int t = threadIdx.x;
    __shared__ float sx[192];
    __shared__ float h1s[128];
    __shared__ float h2s[64];
    if (t < 192) {
        int l = t >> 6, k = t & 63;
        float s = 0.f;
#pragma unroll
        for (int b = 0; b < 32; ++b)
            s += part2[((size_t)l * 32 + b) * (NCFG * HDIM) + c * HDIM + k];
        sx[t] = s;
    }
    __syncthreads();
    if (t < 128) {
        float s = p1b[t];
        for (int d = 0; d < 192; ++d) s += sx[d] * p1w[d * 128 + t];
        h1s[t] = fmaxf(s, 0.f);
    }
    __syncthreads();
    if (t < 64) {
        float s = p2b[t];
        for (int d = 0; d < 128; ++d) s += h1s[d] * p2w[d * 64 + t];
        h2s[t] = fmaxf(s, 0.f);
    }
    __syncthreads();
    if (t == 0) {
        float s = p3b[0];
        for (int d = 0; d < 64; ++d) s += h2s[d] * p3w[d];
        out[c] = s;
    }
}

extern "C" void kernel_launch(void* const* d_in, const int* in_sizes, int n_in,
                              void* d_out, int out_size, void* d_ws, size_t ws_size,
                              hipStream_t stream) {
    const float* nf  = (const float*)d_in[0];
    const int*   opc = (const int*)d_in[1];
    const int*   ei  = (const int*)d_in[2];
    const float* cf  = (const float*)d_in[3];
    const float* ope = (const float*)d_in[4];
    const float* ws0 = (const float*)d_in[5];
    const float* wn0 = (const float*)d_in[6];
    const float* b0  = (const float*)d_in[7];
    const float* wsl = (const float*)d_in[8];
    const float* wnl = (const float*)d_in[9];
    const float* bl  = (const float*)d_in[10];
    const float* skw = (const float*)d_in[11];
    const float* skb = (const float*)d_in[12];
    const float* p1w = (const float*)d_in[13];
    const float* p1b = (const float*)d_in[14];
    const float* p2w = (const float*)d_in[15];
    const float* p2b = (const float*)d_in[16];
    const float* p3w = (const float*)d_in[17];
    const float* p3b = (const float*)d_in[18];
    float* out = (float*)d_out;

    char* w = (char*)d_ws;
    auto alloc = [&](size_t bytes) {
        char* p = w;
        w += (bytes + 255) & ~(size_t)255;
        return p;
    };
    int* deg      = (int*)alloc(N_NODESC * 4);   // deg+fill adjacent: one memset
    int* fill     = (int*)alloc(N_NODESC * 4);
    int* row_ptr  = (int*)alloc((N_NODESC + 1) * 4);
    int* col      = (int*)alloc(2 * N_EDGESC * 4);
    float* xs     = (float*)alloc((size_t)N_NODESC * HDIM * 4);
    float* yn     = (float*)alloc((size_t)N_NODESC * HDIM * 4);
    float* Fc     = (float*)alloc(NCFG * HDIM * 4);
    float* Gc     = (float*)alloc(NCFG * HDIM * 4);
    float* part2  = (float*)alloc(3 * 32 * NCFG * HDIM * 4);
    ushort* frag  = (ushort*)alloc(7 * 4096 * 2);
    float* pAll   = (float*)alloc((size_t)3 * NBLK * NCFG * HDIM * 4);
    ushort* h0    = (ushort*)alloc((size_t)N_NODESC * NCFG * HDIM * 2);
    ushort* h1    = (ushort*)alloc((size_t)N_NODESC * NCFG * HDIM * 2);

    float* p0 = pAll;
    float* p1 = pAll + (size_t)NBLK * (NCFG * HDIM);
    float* p2 = pAll + (size_t)2 * NBLK * (NCFG * HDIM);

    hipMemsetAsync(deg, 0, ((N_NODESC * 4 + 255) & ~(size_t)255) * 2, stream);
    k_deg<<<(2 * N_EDGESC + 255) / 256, 256, 0, stream>>>(ei, deg);
    k_scan<<<1, 1024, 0, stream>>>(deg, row_ptr);
    k_fill<<<(2 * N_EDGESC + 255) / 256, 256, 0, stream>>>(ei, row_ptr, fill, col);
    k_pack<<<8, 512, 0, stream>>>(skw, wsl, wnl, cf, ws0, wn0, b0, frag, Fc, Gc);
    k_proj<<<(N_NODESC * HDIM + 255) / 256, 256, 0, stream>>>(nf, opc, ope, ws0, wn0, xs, yn);

    k_h0skip<<<NBLK, 256, 0, stream>>>(xs, yn, Fc, Gc, row_ptr, col, frag, skb, h0, p0);
    k_sage_mfma<1><<<NBLK, 256, 0, stream>>>(
        h0, h1, frag + 1 * 4096, frag + 2 * 4096, frag + 3 * 4096,
        bl, skb + 64, row_ptr, col, p1);
    k_sage_mfma<0><<<NBLK, 256, 0, stream>>>(
        h1, (ushort*)nullptr, frag + 4 * 4096, frag + 5 * 4096, frag + 6 * 4096,
        bl + 64, skb + 2 * 64, row_ptr, col, p2);

    dim3 gA(8, 32, 3);
    k_redA<<<gA, 256, 0, stream>>>(pAll, part2);
    k_mlp<<<NCFG, 256, 0, stream>>>(part2, p1w, p1b, p2w, p2b, p3w, p3b, out);
}

// Round 12
// 146.200 us; speedup vs baseline: 1.1743x; 1.0993x over previous
//
#include <hip/hip_runtime.h>

#define N_NODESC 5000
#define N_EDGESC 8000
#define NCFG 32
#define HDIM 64
#define NF_DIM 140
#define OPE_DIM 8
#define XN_DIM 148
#define CF_DIM 24
#define NBLK 1250            // one wave per node: 1250 blocks x 4 waves = 5000 waves

using f32x4 = __attribute__((ext_vector_type(4))) float;
using bf16x8 = __attribute__((ext_vector_type(8))) short;

__device__ __forceinline__ ushort f2b(float f) {
    uint u = __float_as_uint(f);
    u += 0x7FFF + ((u >> 16) & 1);
    return (ushort)(u >> 16);
}
__device__ __forceinline__ float b2f(ushort u) {
    return __uint_as_float(((uint)u) << 16);
}

// ---------------- merged prologue: frag-pack + Fc/Gc | degree count | layer-0 projection ----------------
// blocks 0..6: pack matrix m=b; block 7: Fc/Gc; blocks 8..39: deg; blocks 40..664: proj.
// Each path is byte-identical work to round-7's k_pack / k_deg / k_proj.
__global__ __launch_bounds__(512) void k_prologue(
    const int* __restrict__ ei, int* __restrict__ deg,
    const float* __restrict__ skw, const float* __restrict__ wsl,
    const float* __restrict__ wnl, const float* __restrict__ cf,
    const float* __restrict__ Ws0, const float* __restrict__ Wn0,
    const float* __restrict__ b0, ushort* __restrict__ frag,
    float* __restrict__ Fc, float* __restrict__ Gc,
    const float* __restrict__ nf, const int* __restrict__ opcode,
    const float* __restrict__ op_emb,
    float* __restrict__ xs, float* __restrict__ yn) {
    int b = blockIdx.x;
    int t = threadIdx.x;
    if (b < 7) {
        const float* W;
        switch (b) {
            case 0: W = skw; break;
            case 1: W = wsl; break;
            case 2: W = wnl; break;
            case 3: W = skw + 4096; break;
            case 4: W = wsl + 4096; break;
            case 5: W = wnl + 4096; break;
            default: W = skw + 8192; break;
        }
        int ktnt = t >> 6, lane = t & 63;
        int kt = ktnt >> 2, nt = ktnt & 3;
        int g = lane >> 4, row16 = lane & 15;
        bf16x8 v;
#pragma unroll
        for (int j = 0; j < 8; ++j)
            v[j] = (short)f2b(W[(kt * 32 + g * 8 + j) * HDIM + nt * 16 + row16]);
        *reinterpret_cast<bf16x8*>(frag + (size_t)b * 4096 + (size_t)t * 8) = v;
    } else if (b == 7) {
        for (int i = t; i < NCFG * HDIM; i += 512) {
            int c = i >> 6, k = i & 63;
            float f = b0[k], g = 0.f;
            for (int d = 0; d < CF_DIM; ++d) {
                float v = cf[c * CF_DIM + d];
                f += v * Ws0[(XN_DIM + d) * HDIM + k];
                g += v * Wn0[(XN_DIM + d) * HDIM + k];
            }
            Fc[i] = f;
            Gc[i] = g;
        }
    } else if (b < 40) {
        int e = (b - 8) * 512 + t;
        if (e < 2 * N_EDGESC) {
            int d = (e < N_EDGESC) ? ei[2 * e + 1] : ei[2 * (e - N_EDGESC)];
            atomicAdd(&deg[d], 1);
        }
    } else {
        int i = (b - 40) * 512 + t;
        if (i < N_NODESC * HDIM) {
            int n = i >> 6, k = i & 63;
            const float* x = nf + (size_t)n * NF_DIM;
            float s = 0.f, y = 0.f;
            for (int d = 0; d < NF_DIM; ++d) {
                float v = x[d];
                s += v * Ws0[d * HDIM + k];
                y += v * Wn0[d * HDIM + k];
            }
            const float* oe = op_emb + (size_t)opcode[n] * OPE_DIM;
#pragma unroll
            for (int d = 0; d < OPE_DIM; ++d) {
                float v = oe[d];
                s += v * Ws0[(NF_DIM + d) * HDIM + k];
                y += v * Wn0[(NF_DIM + d) * HDIM + k];
            }
            xs[i] = s;
            yn[i] = y;
        }
    }
}

// ---------------- graph build (scan + fill, unchanged from round 7) ----------------
__global__ void k_scan(const int* __restrict__ deg, int* __restrict__ row_ptr) {
    __shared__ int ssum[1024];
    int t = threadIdx.x;
    const int per = (N_NODESC + 1023) / 1024;
    int vals[8];
    int loc = 0;
    for (int i = 0; i < per; ++i) {
        int idx = t * per + i;
        int v = (idx < N_NODESC) ? deg[idx] : 0;
        vals[i] = loc;
        loc += v;
    }
    ssum[t] = loc;
    __syncthreads();
    for (int s = 1; s < 1024; s <<= 1) {
        int v = (t >= s) ? ssum[t - s] : 0;
        __syncthreads();
        ssum[t] += v;
        __syncthreads();
    }
    int excl = ssum[t] - loc;
    for (int i = 0; i < per; ++i) {
        int idx = t * per + i;
        if (idx < N_NODESC) row_ptr[idx] = excl + vals[i];
    }
    if (t == 1023) row_ptr[N_NODESC] = ssum[1023];
}

__global__ void k_fill(const int* __restrict__ ei, const int* __restrict__ row_ptr,
                       int* __restrict__ fill, int* __restrict__ col) {
    int t = blockIdx.x * blockDim.x + threadIdx.x;
    if (t >= 2 * N_EDGESC) return;
    int s, d;
    if (t < N_EDGESC) { s = ei[2 * t]; d = ei[2 * t + 1]; }
    else { int e = t - N_EDGESC; s = ei[2 * e + 1]; d = ei[2 * e]; }
    int pos = atomicAdd(&fill[d], 1);
    col[row_ptr[d] + pos] = s;
}

// En = xs + mean_neigh(yn)   (aggregation in 64-dim h space; unchanged from round 7)
__global__ void k_En2(const float* __restrict__ xs, const float* __restrict__ yn,
                      const int* __restrict__ row_ptr, const int* __restrict__ col,
                      float* __restrict__ En) {
    int t = blockIdx.x * blockDim.x + threadIdx.x;
    if (t >= N_NODESC * HDIM) return;
    int n = t >> 6, k = t & 63;
    int rs = row_ptr[n], re = row_ptr[n + 1];
    float s = 0.f;
    for (int j = rs; j < re; ++j) s += yn[col[j] * HDIM + k];
    float inv = (re > rs) ? 1.f / (float)(re - rs) : 0.f;
    En[t] = xs[t] + s * inv;
}

// ---------------- fused h0 build + skip0 head (one wave per node; unchanged from round 7) ----------------
__global__ __launch_bounds__(256) void k_h0skip(
    const float* __restrict__ En, const float* __restrict__ Fc,
    const float* __restrict__ Gc, const int* __restrict__ row_ptr,
    const ushort* __restrict__ fragSk, const float* __restrict__ skB,
    ushort* __restrict__ h0, float* __restrict__ partials) {
    __shared__ float sred[4][NCFG * HDIM];
    int lane = threadIdx.x & 63;
    int row16 = lane & 15, g = lane >> 4;
    int w = threadIdx.x >> 6;
    int n = (blockIdx.x * 256 + threadIdx.x) >> 6;

    bf16x8 bSk[2][4];
#pragma unroll
    for (int kt = 0; kt < 2; ++kt)
#pragma unroll
        for (int nt = 0; nt < 4; ++nt)
            bSk[kt][nt] = *reinterpret_cast<const bf16x8*>(
                fragSk + ((kt * 4 + nt) * 64 + lane) * 8);
    float sb[4];
#pragma unroll
    for (int nt = 0; nt < 4; ++nt) sb[nt] = skB[nt * 16 + row16];

    float fcv[2][2][8], gcv[2][2][8];
#pragma unroll
    for (int mt = 0; mt < 2; ++mt)
#pragma unroll
        for (int kt = 0; kt < 2; ++kt) {
            int base = (row16 + 16 * mt) * HDIM + kt * 32 + g * 8;
            float4 f0 = *(const float4*)&Fc[base];
            float4 f1 = *(const float4*)&Fc[base + 4];
            float4 g0 = *(const float4*)&Gc[base];
            float4 g1 = *(const float4*)&Gc[base + 4];
            fcv[mt][kt][0] = f0.x; fcv[mt][kt][1] = f0.y; fcv[mt][kt][2] = f0.z; fcv[mt][kt][3] = f0.w;
            fcv[mt][kt][4] = f1.x; fcv[mt][kt][5] = f1.y; fcv[mt][kt][6] = f1.z; fcv[mt][kt][7] = f1.w;
            gcv[mt][kt][0] = g0.x; gcv[mt][kt][1] = g0.y; gcv[mt][kt][2] = g0.z; gcv[mt][kt][3] = g0.w;
            gcv[mt][kt][4] = g1.x; gcv[mt][kt][5] = g1.y; gcv[mt][kt][6] = g1.z; gcv[mt][kt][7] = g1.w;
        }

    float sc = (row_ptr[n + 1] > row_ptr[n]) ? 1.f : 0.f;
    const float* enp = En + (size_t)n * HDIM;
    float en[2][8];
#pragma unroll
    for (int kt = 0; kt < 2; ++kt) {
        float4 e0 = *(const float4*)&enp[kt * 32 + g * 8];
        float4 e1 = *(const float4*)&enp[kt * 32 + g * 8 + 4];
        en[kt][0] = e0.x; en[kt][1] = e0.y; en[kt][2] = e0.z; en[kt][3] = e0.w;
        en[kt][4] = e1.x; en[kt][5] = e1.y; en[kt][6] = e1.z; en[kt][7] = e1.w;
    }
    bf16x8 aH[2][2];
#pragma unroll
    for (int mt = 0; mt < 2; ++mt)
#pragma unroll
        for (int kt = 0; kt < 2; ++kt) {
            bf16x8 a;
#pragma unroll
            for (int j = 0; j < 8; ++j) {
                float hv = fmaxf(en[kt][j] + fcv[mt][kt][j] + sc * gcv[mt][kt][j], 0.f);
                a[j] = (short)f2b(hv);
            }
            aH[mt][kt] = a;
            *reinterpret_cast<bf16x8*>(
                h0 + (size_t)n * (NCFG * HDIM) + (row16 + 16 * mt) * HDIM + kt * 32 + g * 8) = a;
        }
    f32x4 skipAcc[2][4];
#pragma unroll
    for (int mt = 0; mt < 2; ++mt)
#pragma unroll
        for (int nt = 0; nt < 4; ++nt) {
            f32x4 c2 = f32x4{0.f, 0.f, 0.f, 0.f};
#pragma unroll
            for (int kt = 0; kt < 2; ++kt)
                c2 = __builtin_amdgcn_mfma_f32_16x16x32_bf16(aH[mt][kt], bSk[kt][nt], c2, 0, 0, 0);
#pragma unroll
            for (int r = 0; r < 4; ++r)
                skipAcc[mt][nt][r] = fmaxf(c2[r] + sb[nt], 0.f);
        }

#pragma unroll
    for (int mt = 0; mt < 2; ++mt)
#pragma unroll
        for (int nt = 0; nt < 4; ++nt)
#pragma unroll
            for (int r = 0; r < 4; ++r)
                sred[w][(16 * mt + 4 * g + r) * HDIM + 16 * nt + row16] = skipAcc[mt][nt][r];
    __syncthreads();
    float* pb = partials + (size_t)blockIdx.x * (NCFG * HDIM);
#pragma unroll
    for (int q = 0; q < 2; ++q) {
        int p = threadIdx.x * 8 + q * 4;
        f32x4 s = *(const f32x4*)&sred[0][p];
        s += *(const f32x4*)&sred[1][p];
        s += *(const f32x4*)&sred[2][p];
        s += *(const f32x4*)&sred[3][p];
        *(f32x4*)&pb[p] = s;
    }
}

// ---------------- fused SAGE layer + out-skip (one wave per node, union LDS; unchanged from round 7) ----------------
template <int STORE_H>
__global__ __launch_bounds__(256) void k_sage_mfma(
    const ushort* __restrict__ h_in, ushort* __restrict__ h_out,
    const ushort* __restrict__ fragWs, const ushort* __restrict__ fragWn,
    const ushort* __restrict__ fragSk,
    const float* __restrict__ bias, const float* __restrict__ skB,
    const int* __restrict__ row_ptr, const int* __restrict__ col,
    float* __restrict__ partials) {
    __shared__ __align__(16) char smem_raw[NCFG * HDIM * 4 * 4];
    int lane = threadIdx.x & 63;
    int row16 = lane & 15, g = lane >> 4;
    int w = threadIdx.x >> 6;
    int n = (blockIdx.x * 256 + threadIdx.x) >> 6;
    ushort* st = (ushort*)smem_raw + (size_t)w * (32 * 72);
    float* sredw = (float*)smem_raw;

    bf16x8 bWs[2][4], bWn[2][4], bSk[2][4];
#pragma unroll
    for (int kt = 0; kt < 2; ++kt)
#pragma unroll
        for (int nt = 0; nt < 4; ++nt) {
            int fo = ((kt * 4 + nt) * 64 + lane) * 8;
            bWs[kt][nt] = *reinterpret_cast<const bf16x8*>(fragWs + fo);
            bWn[kt][nt] = *reinterpret_cast<const bf16x8*>(fragWn + fo);
            bSk[kt][nt] = *reinterpret_cast<const bf16x8*>(fragSk + fo);
        }
    float bb[4], sb[4];
#pragma unroll
    for (int nt = 0; nt < 4; ++nt) {
        bb[nt] = bias[nt * 16 + row16];
        sb[nt] = skB[nt * 16 + row16];
    }

    int loff[2][2];
#pragma unroll
    for (int mt = 0; mt < 2; ++mt)
#pragma unroll
        for (int kt = 0; kt < 2; ++kt)
            loff[mt][kt] = (row16 + 16 * mt) * HDIM + kt * 32 + g * 8;

    const ushort* hb = h_in + (size_t)n * (NCFG * HDIM);
    bf16x8 aS[2][2];
#pragma unroll
    for (int mt = 0; mt < 2; ++mt)
#pragma unroll
        for (int kt = 0; kt < 2; ++kt)
            aS[mt][kt] = *reinterpret_cast<const bf16x8*>(hb + loff[mt][kt]);

    float agg[2][2][8];
#pragma unroll
    for (int mt = 0; mt < 2; ++mt)
#pragma unroll
        for (int kt = 0; kt < 2; ++kt)
#pragma unroll
            for (int j = 0; j < 8; ++j) agg[mt][kt][j] = 0.f;
    int rs = row_ptr[n], re = row_ptr[n + 1];
    for (int e = rs; e < re; ++e) {
        const ushort* nb = h_in + (size_t)col[e] * (NCFG * HDIM);
#pragma unroll
        for (int mt = 0; mt < 2; ++mt)
#pragma unroll
            for (int kt = 0; kt < 2; ++kt) {
                bf16x8 u = *reinterpret_cast<const bf16x8*>(nb + loff[mt][kt]);
#pragma unroll
                for (int j = 0; j < 8; ++j) agg[mt][kt][j] += b2f((ushort)u[j]);
            }
    }
    float inv = (re > rs) ? 1.f / (float)(re - rs) : 0.f;
    bf16x8 aA[2][2];
#pragma unroll
    for (int mt = 0; mt < 2; ++mt)
#pragma unroll
        for (int kt = 0; kt < 2; ++kt)
#pragma unroll
            for (int j = 0; j < 8; ++j)
                aA[mt][kt][j] = (short)f2b(agg[mt][kt][j] * inv);

    f32x4 C[2][4];
#pragma unroll
    for (int mt = 0; mt < 2; ++mt)
#pragma unroll
        for (int nt = 0; nt < 4; ++nt) {
            f32x4 c = f32x4{0.f, 0.f, 0.f, 0.f};
#pragma unroll
            for (int kt = 0; kt < 2; ++kt) {
                c = __builtin_amdgcn_mfma_f32_16x16x32_bf16(aS[mt][kt], bWs[kt][nt], c, 0, 0, 0);
                c = __builtin_amdgcn_mfma_f32_16x16x32_bf16(aA[mt][kt], bWn[kt][nt], c, 0, 0, 0);
            }
            C[mt][nt] = c;
        }

#pragma unroll
    for (int mt = 0; mt < 2; ++mt)
#pragma unroll
        for (int nt = 0; nt < 4; ++nt)
#pragma unroll
            for (int r = 0; r < 4; ++r) {
                float hv = fmaxf(C[mt][nt][r] + bb[nt], 0.f);
                st[(16 * mt + 4 * g + r) * 72 + 16 * nt + row16] = f2b(hv);
            }
    asm volatile("s_waitcnt lgkmcnt(0)" ::: "memory");

    if (STORE_H) {
#pragma unroll
        for (int i = 0; i < 4; ++i) {
            int e2 = i * 512 + lane * 8;
            int cc = e2 >> 6, dd = e2 & 63;
            bf16x8 v = *reinterpret_cast<const bf16x8*>(st + cc * 72 + dd);
            *reinterpret_cast<bf16x8*>(h_out + (size_t)n * (NCFG * HDIM) + e2) = v;
        }
    }

    bf16x8 aH[2][2];
#pragma unroll
    for (int mt = 0; mt < 2; ++mt)
#pragma unroll
        for (int kt = 0; kt < 2; ++kt)
            aH[mt][kt] = *reinterpret_cast<const bf16x8*>(
                st + (row16 + 16 * mt) * 72 + kt * 32 + g * 8);
    asm volatile("s_waitcnt lgkmcnt(0)" ::: "memory");
    f32x4 skipAcc[2][4];
#pragma unroll
    for (int mt = 0; mt < 2; ++mt)
#pragma unroll
        for (int nt = 0; nt < 4; ++nt) {
            f32x4 c2 = f32x4{0.f, 0.f, 0.f, 0.f};
#pragma unroll
            for (int kt = 0; kt < 2; ++kt)
                c2 = __builtin_amdgcn_mfma_f32_16x16x32_bf16(aH[mt][kt], bSk[kt][nt], c2, 0, 0, 0);
#pragma unroll
            for (int r = 0; r < 4; ++r)
                skipAcc[mt][nt][r] = fmaxf(c2[r] + sb[nt], 0.f);
        }

    __syncthreads();   // all waves done with stage region before sred overlay
#pragma unroll
    for (int mt = 0; mt < 2; ++mt)
#pragma unroll
        for (int nt = 0; nt < 4; ++nt)
#pragma unroll
            for (int r = 0; r < 4; ++r)
                sredw[(size_t)w * (NCFG * HDIM) +
                      (16 * mt + 4 * g + r) * HDIM + 16 * nt + row16] = skipAcc[mt][nt][r];
    __syncthreads();
    float* pb = partials + (size_t)blockIdx.x * (NCFG * HDIM);
#pragma unroll
    for (int q = 0; q < 2; ++q) {
        int p = threadIdx.x * 8 + q * 4;
        f32x4 s = *(const f32x4*)&sredw[0 * NCFG * HDIM + p];
        s += *(const f32x4*)&sredw[1 * NCFG * HDIM + p];
        s += *(const f32x4*)&sredw[2 * NCFG * HDIM + p];
        s += *(const f32x4*)&sredw[3 * NCFG * HDIM + p];
        *(f32x4*)&pb[p] = s;
    }
}

// ---------------- reduce stage A over all 3 layers ----------------
__global__ __launch_bounds__(256) void k_redA(const float* __restrict__ pAll,
                                              float* __restrict__ part2) {
    int i = blockIdx.x * 256 + threadIdx.x;   // 0..2047
    int jb = blockIdx.y;                      // 0..31
    int l = blockIdx.z;                       // 0..2
    const int seg = (NBLK + 31) / 32;         // 40
    const float* base = pAll + (size_t)l * NBLK * (NCFG * HDIM);
    float s = 0.f;
    for (int q = 0; q < seg; ++q) {
        int b = jb * seg + q;
        if (b < NBLK) s += base[(size_t)b * (NCFG * HDIM) + i];
    }
    part2[((size_t)l * 32 + jb) * (NCFG * HDIM) + i] = s;
}

// ---------------- final MLP (stage-B reduce folded in) ----------------
__global__ void k_mlp(const float* __restrict__ part2,
                      const float* __restrict__ p1w, const float* __restrict__ p1b,
                      const float* __restrict__ p2w, const float* __restrict__ p2b,
                      const float* __restrict__ p3w, const float* __restrict__ p3b,
                      float* __restrict__ out) {
    int c = blockIdx.x;
    int t = threadIdx.x;
    __shared__ float sx[192];
    __shared__ float h1s[128];
    __shared__ float h2s[64];
    if (t < 192) {
        int l = t >> 6, k = t & 63;
        float s = 0.f;
#pragma unroll
        for (int b = 0; b < 32; ++b)
            s += part2[((size_t)l * 32 + b) * (NCFG * HDIM) + c * HDIM + k];
        sx[t] = s;
    }
    __syncthreads();
    if (t < 128) {
        float s = p1b[t];
        for (int d = 0; d < 192; ++d) s += sx[d] * p1w[d * 128 + t];
        h1s[t] = fmaxf(s, 0.f);
    }
    __syncthreads();
    if (t < 64) {
        float s = p2b[t];
        for (int d = 0; d < 128; ++d) s += h1s[d] * p2w[d * 64 + t];
        h2s[t] = fmaxf(s, 0.f);
    }
    __syncthreads();
    if (t == 0) {
        float s = p3b[0];
        for (int d = 0; d < 64; ++d) s += h2s[d] * p3w[d];
        out[c] = s;
    }
}

extern "C" void kernel_launch(void* const* d_in, const int* in_sizes, int n_in,
                              void* d_out, int out_size, void* d_ws, size_t ws_size,
                              hipStream_t stream) {
    const float* nf  = (const float*)d_in[0];
    const int*   opc = (const int*)d_in[1];
    const int*   ei  = (const int*)d_in[2];
    const float* cf  = (const float*)d_in[3];
    const float* ope = (const float*)d_in[4];
    const float* ws0 = (const float*)d_in[5];
    const float* wn0 = (const float*)d_in[6];
    const float* b0  = (const float*)d_in[7];
    const float* wsl = (const float*)d_in[8];
    const float* wnl = (const float*)d_in[9];
    const float* bl  = (const float*)d_in[10];
    const float* skw = (const float*)d_in[11];
    const float* skb = (const float*)d_in[12];
    const float* p1w = (const float*)d_in[13];
    const float* p1b = (const float*)d_in[14];
    const float* p2w = (const float*)d_in[15];
    const float* p2b = (const float*)d_in[16];
    const float* p3w = (const float*)d_in[17];
    const float* p3b = (const float*)d_in[18];
    float* out = (float*)d_out;

    char* w = (char*)d_ws;
    auto alloc = [&](size_t bytes) {
        char* p = w;
        w += (bytes + 255) & ~(size_t)255;
        return p;
    };
    int* deg      = (int*)alloc(N_NODESC * 4);   // deg+fill adjacent: one memset
    int* fill     = (int*)alloc(N_NODESC * 4);
    int* row_ptr  = (int*)alloc((N_NODESC + 1) * 4);
    int* col      = (int*)alloc(2 * N_EDGESC * 4);
    float* xs     = (float*)alloc((size_t)N_NODESC * HDIM * 4);
    float* yn     = (float*)alloc((size_t)N_NODESC * HDIM * 4);
    float* En     = (float*)alloc((size_t)N_NODESC * HDIM * 4);
    float* Fc     = (float*)alloc(NCFG * HDIM * 4);
    float* Gc     = (float*)alloc(NCFG * HDIM * 4);
    float* part2  = (float*)alloc(3 * 32 * NCFG * HDIM * 4);
    ushort* frag  = (ushort*)alloc(7 * 4096 * 2);
    float* pAll   = (float*)alloc((size_t)3 * NBLK * NCFG * HDIM * 4);
    ushort* h0    = (ushort*)alloc((size_t)N_NODESC * NCFG * HDIM * 2);
    ushort* h1    = (ushort*)alloc((size_t)N_NODESC * NCFG * HDIM * 2);

    float* p0 = pAll;
    float* p1 = pAll + (size_t)NBLK * (NCFG * HDIM);
    float* p2 = pAll + (size_t)2 * NBLK * (NCFG * HDIM);

    // deg and fill are adjacent (each padded to a 256B boundary): single memset covers both
    hipMemsetAsync(deg, 0, ((N_NODESC * 4 + 255) & ~(size_t)255) * 2, stream);
    // merged prologue: frag pack + Fc/Gc + degree count + layer-0 projection (independent works)
    const int PRO_BLKS = 40 + (N_NODESC * HDIM + 511) / 512;   // 8 pack + 32 deg + 625 proj
    k_prologue<<<PRO_BLKS, 512, 0, stream>>>(ei, deg, skw, wsl, wnl, cf, ws0, wn0, b0,
                                             frag, Fc, Gc, nf, opc, ope, xs, yn);
    k_scan<<<1, 1024, 0, stream>>>(deg, row_ptr);
    k_fill<<<(2 * N_EDGESC + 255) / 256, 256, 0, stream>>>(ei, row_ptr, fill, col);
    k_En2<<<(N_NODESC * HDIM + 255) / 256, 256, 0, stream>>>(xs, yn, row_ptr, col, En);

    k_h0skip<<<NBLK, 256, 0, stream>>>(En, Fc, Gc, row_ptr, frag, skb, h0, p0);
    k_sage_mfma<1><<<NBLK, 256, 0, stream>>>(
        h0, h1, frag + 1 * 4096, frag + 2 * 4096, frag + 3 * 4096,
        bl, skb + 64, row_ptr, col, p1);
    k_sage_mfma<0><<<NBLK, 256, 0, stream>>>(
        h1, (ushort*)nullptr, frag + 4 * 4096, frag + 5 * 4096, frag + 6 * 4096,
        bl + 64, skb + 2 * 64, row_ptr, col, p2);

    dim3 gA(8, 32, 3);
    k_redA<<<gA, 256, 0, stream>>>(pAll, part2);
    k_mlp<<<NCFG, 256, 0, stream>>>(part2, p1w, p1b, p2w, p2b, p3w, p3b, out);
}